// Round 13
// baseline (79.484 us; speedup 1.0000x reference)
//
#include <hip/hip_runtime.h>

#define WSTRIDE 8704            // padded row stride for wab (shifted layout)
#define WTSTRIDE (512 * 128)    // per-jt tile in repacked Wt

__device__ __forceinline__ float lrelu(float x) { return x > 0.0f ? x : 0.01f * x; }

// h0T[j][b] = lrelu(sum_l z[b][l]*W0[l][j] + b0[j]); one block per j, lane = b
__global__ __launch_bounds__(128) void h0T_kernel(const float* __restrict__ z,
                                                  const float* __restrict__ W,
                                                  const float* __restrict__ bias,
                                                  float* __restrict__ h0T) {
    int j = blockIdx.x;          // 0..511
    int b = threadIdx.x;         // 0..127
    float zr[16];
    *(float4*)&zr[0]  = *(const float4*)&z[b * 16 + 0];
    *(float4*)&zr[4]  = *(const float4*)&z[b * 16 + 4];
    *(float4*)&zr[8]  = *(const float4*)&z[b * 16 + 8];
    *(float4*)&zr[12] = *(const float4*)&z[b * 16 + 12];
    float acc = bias[j];
#pragma unroll
    for (int l = 0; l < 16; ++l) acc = fmaf(zr[l], W[l * 512 + j], acc);
    h0T[j * 128 + b] = lrelu(acc);
}

// OT[j][b] = lrelu(sum_k At[k][b]*W[k][j] + bias[j])  — R5-proven config.
__global__ __launch_bounds__(512) void gemmT_kernel(const float* __restrict__ At,
                                                    const float* __restrict__ W,
                                                    const float* __restrict__ bias,
                                                    float* __restrict__ OT) {
    __shared__ __align__(16) float As[512][4];   // 8 KB
    __shared__ float red[8][64][5];              // 10 KB
    int jt = blockIdx.x & 7;
    int bt = blockIdx.x >> 3;          // 0..31
    int tid = threadIdx.x;
    int lane = tid & 63;
    int wid  = __builtin_amdgcn_readfirstlane(tid >> 6);  // 0..7
    int b0 = bt * 4;
#pragma unroll
    for (int r = 0; r < 2; ++r) {
        int p = r * 512 + tid;
        int k = p >> 1, q = p & 1;
        *(float2*)&As[k][q * 2] = *(const float2*)&At[k * 128 + b0 + q * 2];
    }
    __syncthreads();
    int j = jt * 64 + lane;
    float acc[4] = {};
    int k0 = wid * 64;
#pragma unroll 8
    for (int kk = 0; kk < 64; ++kk) {
        int k = k0 + kk;
        float4 a = *(const float4*)&As[k][0];   // LDS broadcast
        float w = W[k * 512 + j];               // coalesced dword
        acc[0] = fmaf(a.x, w, acc[0]);
        acc[1] = fmaf(a.y, w, acc[1]);
        acc[2] = fmaf(a.z, w, acc[2]);
        acc[3] = fmaf(a.w, w, acc[3]);
    }
#pragma unroll
    for (int i = 0; i < 4; ++i) red[wid][lane][i] = acc[i];
    __syncthreads();
    if (tid < 256) {
        int jj = tid >> 2;
        int bb = tid & 3;
        float s = 0.f;
#pragma unroll
        for (int w = 0; w < 8; ++w) s += red[w][jj][bb];
        int jg = jt * 64 + jj;
        OT[jg * 128 + b0 + bb] = lrelu(s + bias[jg]);
    }
}

// Repack hWo[512][8450] -> Wt[67][512][128] (k-major, 16B-aligned tiles).
// jt 66 sources cols 8448..8575 clamped to 8449 (dups discarded at wab store).
// grid (67, 32): blockIdx.x = jt, blockIdx.y = kq (16 k each). 256 thr.
__global__ __launch_bounds__(256) void repack_kernel(const float* __restrict__ W,
                                                     float* __restrict__ Wt) {
    int jt = blockIdx.x;
    int kq = blockIdx.y;
    int tid = threadIdx.x;
    int kl = tid >> 4;             // 0..15
    int jgq = tid & 15;            // 0..15
    int k = kq * 16 + kl;
    int c0 = jt * 128 + jgq * 8;
    float v[8];
    if (jt < 66) {
        const float* src = W + (size_t)k * 8450 + c0;   // 8B aligned (c0 even)
#pragma unroll
        for (int e = 0; e < 4; ++e)
            *(float2*)&v[e * 2] = *(const float2*)(src + e * 2);
    } else {
#pragma unroll
        for (int e = 0; e < 8; ++e) {
            int c = c0 + e;
            v[e] = W[(size_t)k * 8450 + (c < 8450 ? c : 8449)];
        }
    }
    float* dst = Wt + (size_t)jt * WTSTRIDE + k * 128 + jgq * 8;  // 16B aligned
    *(float4*)&dst[0] = make_float4(v[0], v[1], v[2], v[3]);
    *(float4*)&dst[4] = make_float4(v[4], v[5], v[6], v[7]);
}

// wab[b][dest(j)] = sum_k At[k][b]*Wt + hbo[j]; dest(j)=j+(j>=65?3:0)
// Tile 128j x 16b x ks4 (256 thr). Lane = (jg 16 x bg 4): jl=8 (TWO aligned
// float4 from the contiguous Wt stream), bb=4 (LDS b128 broadcast). acc=32 regs.
// Grid 576: bx = ((jt>>3)*8 + bt)*8 + (jt&7) -> bx%8 = jt%8 (XCD-grouped);
// jt>=67 idles. LDS 32 KB exact: As[512][16] overlaid by XOR-swizzled reduce.
__global__ __launch_bounds__(256, 4) void wabT_kernel(const float* __restrict__ At,
                                                      const float* __restrict__ Wt,
                                                      const float* __restrict__ bias,
                                                      float* __restrict__ wab) {
    __shared__ __align__(16) float smem[4 * 64 * 32];   // 32 KB
    float (*As)[16] = (float (*)[16])smem;              // 512 x 16 (overlay)
    int tid = threadIdx.x;
    int lane = tid & 63;
    int wid = __builtin_amdgcn_readfirstlane(tid >> 6);  // 0..3
    int q = blockIdx.x >> 3;           // 0..71
    int c = blockIdx.x & 7;
    int jt = (q >> 3) * 8 + c;         // 0..71; jt%8 == bx%8
    int bt = q & 7;                    // 0..7
    if (jt >= 67) return;
    int b0blk = bt * 16;
    // stage At[0:512][b0blk..+16] -> As (8 float4 per thread)
#pragma unroll
    for (int r = 0; r < 8; ++r) {
        int p = r * 256 + tid;         // 0..2047
        int k = p >> 2, h = (p & 3) * 4;
        *(float4*)&As[k][h] = *(const float4*)&At[k * 128 + b0blk + h];
    }
    __syncthreads();
    int jg = lane & 15;
    int bg = lane >> 4;                // 0..3
    int k0 = wid * 128;
    const float* __restrict__ Wp = Wt + (size_t)jt * WTSTRIDE + k0 * 128 + jg * 8;
    float acc[4][8];
#pragma unroll
    for (int i = 0; i < 4; ++i)
#pragma unroll
        for (int jj = 0; jj < 8; ++jj) acc[i][jj] = 0.f;
#pragma unroll 4
    for (int kk = 0; kk < 128; ++kk) {
        float4 a = *(const float4*)&As[k0 + kk][bg * 4];   // LDS b128 broadcast
        const float* wr = Wp + kk * 128;                   // contiguous stream
        float4 w0 = *(const float4*)(wr + 0);
        float4 w1 = *(const float4*)(wr + 4);
        float av[4] = {a.x, a.y, a.z, a.w};
        float wv[8] = {w0.x, w0.y, w0.z, w0.w, w1.x, w1.y, w1.z, w1.w};
#pragma unroll
        for (int i = 0; i < 4; ++i)
#pragma unroll
            for (int jj = 0; jj < 8; ++jj)
                acc[i][jj] = fmaf(av[i], wv[jj], acc[i][jj]);
    }
    __syncthreads();                   // As dead; overlay reduce
    // dump: bank = e ^ lane -> 2-way (free)
#pragma unroll
    for (int i = 0; i < 4; ++i)
#pragma unroll
        for (int jj = 0; jj < 8; ++jj) {
            int e = i * 8 + jj;
            smem[wid * 2048 + lane * 32 + (e ^ (lane & 31))] = acc[i][jj];
        }
    __syncthreads();
    // final: thread t -> b-local bl=t>>4, j = (t&15)*8 + r
    {
        int bl = tid >> 4;             // 0..15
        int jgr = tid & 15;
        int lane_r = (bl >> 2) * 16 + jgr;
        int swz = lane_r & 31;
        float* drow = wab + (size_t)(b0blk + bl) * WSTRIDE;
#pragma unroll
        for (int r = 0; r < 8; ++r) {
            int e = (bl & 3) * 8 + r;
            int o = lane_r * 32 + (e ^ swz);
            float s = smem[o] + smem[2048 + o] + smem[4096 + o] + smem[6144 + o];
            int jglob = jt * 128 + jgr * 8 + r;
            if (jglob < 8450)
                drow[jglob + (jglob >= 65 ? 3 : 0)] = s + bias[jglob];
        }
    }
}

// Decoder (R9-proven). wab row (shifted): w0[0:64], b0[64], pad[65:68),
// W1[68:4164), b1[4164:4228), W2[4228:8324), b2[8324:8388), w3[8388:8452), b3[8452].
// Grid 256 = (b, g-half); 512 thr = 8 waves, wave owns 8 j. lane = g.
__global__ __launch_bounds__(512) void decoder_kernel(const float* __restrict__ wab,
                                                      const float* __restrict__ logP,
                                                      float* __restrict__ out) {
    __shared__ float hX[64 * 65];      // 16.6 KB, h[j][g]
    __shared__ float hY[64 * 65];
    __shared__ float red[8][68];
    int b  = blockIdx.x >> 1;
    int gh = blockIdx.x & 1;
    int tid = threadIdx.x;
    int lane = tid & 63;
    int jq = (tid >> 6) * 8;           // vector path (no readfirstlane)
    int g = gh * 64 + lane;
    bool act = g < 100;
    const float* __restrict__ row = wab + (size_t)b * WSTRIDE;
    float x0 = act ? logP[b * 100 + g] * (1.0f / 3.0f) : 0.0f;
    float c0 = row[64];
#pragma unroll
    for (int t = 0; t < 8; ++t)
        hX[(jq + t) * 65 + lane] = __sinf(30.0f * fmaf(x0, row[jq + t], c0));
    __syncthreads();
    // layer 1
    {
        float a[8];
#pragma unroll
        for (int t = 0; t < 8; ++t) a[t] = row[4164 + jq + t];
#pragma unroll 4
        for (int i = 0; i < 64; ++i) {
            float hi = hX[i * 65 + lane];
            const float* wr = row + 68 + i * 64 + jq;   // 16B aligned
            float4 w0 = *(const float4*)&wr[0];
            float4 w1 = *(const float4*)&wr[4];
            a[0] = fmaf(hi, w0.x, a[0]);  a[1] = fmaf(hi, w0.y, a[1]);
            a[2] = fmaf(hi, w0.z, a[2]);  a[3] = fmaf(hi, w0.w, a[3]);
            a[4] = fmaf(hi, w1.x, a[4]);  a[5] = fmaf(hi, w1.y, a[5]);
            a[6] = fmaf(hi, w1.z, a[6]);  a[7] = fmaf(hi, w1.w, a[7]);
        }
#pragma unroll
        for (int t = 0; t < 8; ++t) hY[(jq + t) * 65 + lane] = __sinf(a[t]);
    }
    __syncthreads();
    // layer 2
    {
        float a[8];
#pragma unroll
        for (int t = 0; t < 8; ++t) a[t] = row[8324 + jq + t];
#pragma unroll 4
        for (int i = 0; i < 64; ++i) {
            float hi = hY[i * 65 + lane];
            const float* wr = row + 4228 + i * 64 + jq;
            float4 w0 = *(const float4*)&wr[0];
            float4 w1 = *(const float4*)&wr[4];
            a[0] = fmaf(hi, w0.x, a[0]);  a[1] = fmaf(hi, w0.y, a[1]);
            a[2] = fmaf(hi, w0.z, a[2]);  a[3] = fmaf(hi, w0.w, a[3]);
            a[4] = fmaf(hi, w1.x, a[4]);  a[5] = fmaf(hi, w1.y, a[5]);
            a[6] = fmaf(hi, w1.z, a[6]);  a[7] = fmaf(hi, w1.w, a[7]);
        }
#pragma unroll
        for (int t = 0; t < 8; ++t) hX[(jq + t) * 65 + lane] = __sinf(a[t]);
    }
    __syncthreads();
    // layer 3
    float p = 0.f;
#pragma unroll
    for (int t = 0; t < 8; ++t)
        p = fmaf(hX[(jq + t) * 65 + lane], row[8388 + jq + t], p);
    red[tid >> 6][lane] = p;
    __syncthreads();
    if (tid < 64 && act) {
        float s = row[8452];
#pragma unroll
        for (int w = 0; w < 8; ++w) s += red[w][lane];
        out[b * 100 + g] = fmaf(s, 500.0f, 1500.0f);
    }
}

extern "C" void kernel_launch(void* const* d_in, const int* in_sizes, int n_in,
                              void* d_out, int out_size, void* d_ws, size_t ws_size,
                              hipStream_t stream) {
    const float* z    = (const float*)d_in[0];
    const float* logP = (const float*)d_in[1];
    const float* hW0  = (const float*)d_in[2];
    const float* hb0  = (const float*)d_in[3];
    const float* hW1  = (const float*)d_in[4];
    const float* hb1  = (const float*)d_in[5];
    const float* hW2  = (const float*)d_in[6];
    const float* hb2  = (const float*)d_in[7];
    const float* hWo  = (const float*)d_in[8];
    const float* hbo  = (const float*)d_in[9];
    float* out = (float*)d_out;

    float* wab = (float*)d_ws;               // 128*8704 floats (4.46 MB)
    float* h0T = wab + 128 * WSTRIDE;        // 512*128
    float* h1T = h0T + 512 * 128;
    float* h2T = h1T + 512 * 128;
    float* Wt  = h2T + 512 * 128;            // 67*512*128 floats (17.6 MB); total ~23 MB

    repack_kernel<<<dim3(67, 32), 256, 0, stream>>>(hWo, Wt);
    h0T_kernel<<<512, 128, 0, stream>>>(z, hW0, hb0, h0T);
    gemmT_kernel<<<256, 512, 0, stream>>>(h0T, hW1, hb1, h1T);
    gemmT_kernel<<<256, 512, 0, stream>>>(h1T, hW2, hb2, h2T);
    wabT_kernel<<<576, 256, 0, stream>>>(h2T, Wt, hbo, wab);
    decoder_kernel<<<256, 512, 0, stream>>>(wab, logP, out);
}